// Round 5
// baseline (347.584 us; speedup 1.0000x reference)
//
#include <hip/hip_runtime.h>
#include <hip/hip_cooperative_groups.h>
#include <math.h>

namespace cg = cooperative_groups;

#define BB 8
#define NN 2000
#define CC 81
#define NPAD 2048
#define MAXI 100
#define HH 512
#define WW 512

// ---------------------------------------------------------------------------
// Single cooperative kernel, 512 blocks x 256 threads (2 blocks/CU, always
// co-resident). Phases separated by grid.sync() instead of kernel launches
// (R4 evidence: ~8-10 us per dispatch gap; grid sync ~1-3 us).
//   P1 refine : 16384 proposal-slots, one wave each, 8 slots/wave (verified
//               R4 k_refine body: shuffle argmax, delta refine, sort key).
//   P2a rankp : 512 (b,ip,jp) tiles == 512 blocks, LDS-broadcast compares.
//   P2b perm  : blocks<64 sum 8 partials -> rank, scatter perm[rank]=i.
//   P3 nms    : blocks<8, wave 0: greedy NMS, register-resident kept set,
//               early-exit at kept==100.
//   P4 mask   : 4096 rows, 8 rows/block, ballot-compact covering boxes.
// All arithmetic identical to the R4 kernels -> bit-identical output.
// ---------------------------------------------------------------------------
__global__ void __launch_bounds__(256, 2)
k_fused(const float* __restrict__ rois, const float* __restrict__ probs,
        const float* __restrict__ deltas, const float* __restrict__ stdv,
        float* __restrict__ score, int* __restrict__ cls,
        int* __restrict__ valid, float* __restrict__ box,
        unsigned long long* __restrict__ gkeys, int* __restrict__ partial,
        int* __restrict__ perm, float* __restrict__ det,
        float* __restrict__ mask) {
#pragma clang fp contract(off)
  __shared__ unsigned long long sk[256];
  __shared__ float lx1[MAXI], lx2[MAXI];
  __shared__ unsigned long long wmask[4];
  cg::grid_group grid = cg::this_grid();
  int tid = threadIdx.x;
  int lane = tid & 63;
  int wv = tid >> 6;

  // ---------------- Phase 1: refine (8 slots per wave) ----------------
  {
    int wave = blockIdx.x * 4 + wv;           // 0..2047
    for (int it = 0; it < 8; ++it) {
      int g = wave + 2048 * it;               // 0..16383
      int b = g >> 11, n = g & (NPAD - 1);
      if (n >= NN) {                          // pad slot: sentinel key + invalid
        if (lane == 0) {
          unsigned u = __float_as_uint(-INFINITY);
          u = ~u;                             // sign set -> ~u
          gkeys[b * NPAD + n] =
              ((unsigned long long)u << 32) | (0xFFFFFFFFu - (unsigned)n);
          valid[b * NPAD + n] = 0;            // NMS may gather this slot
        }
        continue;
      }
      const float* pp = probs + ((size_t)b * NN + n) * CC;
      float best = -INFINITY;
      int bc = CC;
      for (int c = lane; c < CC; c += 64) {
        float p = pp[c];
        if (p > best) { best = p; bc = c; }   // per-lane stride keeps first max
      }
      // cross-lane argmax, first-occurrence tie-break (smaller class wins)
      for (int off = 32; off; off >>= 1) {
        float ob = __shfl_xor(best, off, 64);
        int oc = __shfl_xor(bc, off, 64);
        if (ob > best || (ob == best && oc < bc)) { best = ob; bc = oc; }
      }
      if (lane == 0) {
        int idx = b * NPAD + n;
        const float* r = rois + ((size_t)b * NN + n) * 4;
        const float* dd = deltas + (((size_t)b * NN + n) * CC + bc) * 4;
        float d0 = dd[0] * stdv[0], d1 = dd[1] * stdv[1];
        float d2 = dd[2] * stdv[2], d3 = dd[3] * stdv[3];
        float y1 = r[0], x1 = r[1], y2 = r[2], x2 = r[3];
        float h = y2 - y1, w = x2 - x1;
        float cy = y1 + 0.5f * h + d0 * h;
        float cx = x1 + 0.5f * w + d1 * w;
        h = h * (float)exp((double)d2);   // double ~= correctly-rounded f32 exp
        w = w * (float)exp((double)d3);
        float ny1 = cy - 0.5f * h, nx1 = cx - 0.5f * w;
        float ny2 = cy + 0.5f * h, nx2 = cx + 0.5f * w;
        ny1 = fminf(fmaxf(ny1, 0.f), 1.f);
        nx1 = fminf(fmaxf(nx1, 0.f), 1.f);
        ny2 = fminf(fmaxf(ny2, 0.f), 1.f);
        nx2 = fminf(fmaxf(nx2, 0.f), 1.f);
        box[idx * 4 + 0] = ny1;
        box[idx * 4 + 1] = nx1;
        box[idx * 4 + 2] = ny2;
        box[idx * 4 + 3] = nx2;
        score[idx] = best;
        cls[idx] = bc;
        int v = (bc > 0 && best >= 0.05f) ? 1 : 0;
        valid[idx] = v;
        float ks = v ? best : -INFINITY;
        unsigned u = __float_as_uint(ks);
        u = (u & 0x80000000u) ? ~u : (u | 0x80000000u);
        gkeys[idx] = ((unsigned long long)u << 32) | (0xFFFFFFFFu - (unsigned)n);
      }
    }
  }
  grid.sync();

  // ---------------- Phase 2a: rank partial counts ----------------
  {
    int blk = blockIdx.x;                 // b*64 + ip*8 + jp, exactly 512
    int jp = blk & 7, ip = (blk >> 3) & 7, b = blk >> 6;
    sk[tid] = gkeys[b * NPAD + jp * 256 + tid];
    unsigned long long myk = gkeys[b * NPAD + ip * 256 + tid];
    __syncthreads();
    int cnt = 0;
#pragma unroll 8
    for (int j = 0; j < 256; j++) cnt += (sk[j] > myk) ? 1 : 0;
    partial[(b * 8 + jp) * NPAD + ip * 256 + tid] = cnt;
  }
  grid.sync();

  // ---------------- Phase 2b: rank sum -> inverse permutation ----------------
  if (blockIdx.x < 64) {
    int t = blockIdx.x * 256 + tid;       // 0..16383
    int b = t >> 11, i = t & (NPAD - 1);
    int rank = 0;
#pragma unroll
    for (int jp = 0; jp < 8; jp++) rank += partial[(b * 8 + jp) * NPAD + i];
    perm[b * NPAD + rank] = i;
  }
  grid.sync();

  // ---------------- Phase 3: greedy NMS (blocks 0..7, wave 0) ----------------
  if (blockIdx.x < BB && tid < 64) {
    int b = blockIdx.x;
    int kept = 0;
    bool done = false;
    float k0y1 = 0.f, k0x1 = 0.f, k0y2 = 0.f, k0x2 = 0.f, k0a = 0.f;
    float k1y1 = 0.f, k1x1 = 0.f, k1y2 = 0.f, k1x2 = 0.f, k1a = 0.f;
    for (int base = 0; base < NN && !done; base += 64) {
      int pi = perm[b * NPAD + base + lane];
      int o = b * NPAD + pi;
      float4 bx = ((const float4*)box)[o];
      int lv = valid[o];
      int lc = cls[o];
      float lsc = score[o];
      int lim = (NN - base < 64) ? (NN - base) : 64;
      for (int j = 0; j < lim; j++) {
        int v = __shfl(lv, j, 64);
        if (!v) { done = true; break; }   // sorted: all invalid at the end
        float y1 = __shfl(bx.x, j, 64);
        float x1 = __shfl(bx.y, j, 64);
        float y2 = __shfl(bx.z, j, 64);
        float x2 = __shfl(bx.w, j, 64);
        int c = __shfl(lc, j, 64);
        float off = 2.0f * (float)c;
        float oy1 = y1 + off, ox1 = x1 + off, oy2 = y2 + off, ox2 = x2 + off;
        float area_i = (oy2 - oy1) * (ox2 - ox1);
        bool pred = false;
        if (lane < kept) {
          float yy1 = fmaxf(oy1, k0y1), xx1 = fmaxf(ox1, k0x1);
          float yy2 = fminf(oy2, k0y2), xx2 = fminf(ox2, k0x2);
          float inter = fmaxf(yy2 - yy1, 0.f) * fmaxf(xx2 - xx1, 0.f);
          float uni = (area_i + k0a) - inter;
          pred = (inter / fmaxf(uni, 1e-12f)) > 0.3f;
        }
        if (64 + lane < kept) {
          float yy1 = fmaxf(oy1, k1y1), xx1 = fmaxf(ox1, k1x1);
          float yy2 = fminf(oy2, k1y2), xx2 = fminf(ox2, k1x2);
          float inter = fmaxf(yy2 - yy1, 0.f) * fmaxf(xx2 - xx1, 0.f);
          float uni = (area_i + k1a) - inter;
          pred = pred || ((inter / fmaxf(uni, 1e-12f)) > 0.3f);
        }
        if (__ballot(pred) == 0ULL) {            // wave-uniform accept
          if (kept < 64) {
            if (lane == kept) { k0y1 = oy1; k0x1 = ox1; k0y2 = oy2; k0x2 = ox2; k0a = area_i; }
          } else {
            if (lane == kept - 64) { k1y1 = oy1; k1x1 = ox1; k1y2 = oy2; k1x2 = ox2; k1a = area_i; }
          }
          float sc = __shfl(lsc, j, 64);
          if (lane == 0) {
            float* dr = det + ((size_t)b * MAXI + kept) * 6;
            dr[0] = y1; dr[1] = x1; dr[2] = y2; dr[3] = x2;
            dr[4] = (float)c; dr[5] = sc;
          }
          kept++;
          if (kept == MAXI) { done = true; break; }
        }
      }
    }
    // zero-fill remaining det rows (d_out is poisoned 0xAA)
    int rem = (MAXI - kept) * 6;
    float* dr0 = det + ((size_t)b * MAXI + kept) * 6;
    for (int t = lane; t < rem; t += 64) dr0[t] = 0.f;
  }
  grid.sync();

  // ---------------- Phase 4: attention mask (8 rows per block) ----------------
  for (int it = 0; it < 8; ++it) {
    int row = blockIdx.x + 512 * it;      // 0..4095
    int h = row & (HH - 1);
    int b = row >> 9;
    __syncthreads();                      // protect LDS reuse across rows
    float ys = ((float)h + 0.5f) * (1.0f / 512.0f);
    bool inb = false;
    float bx1 = 0.f, bx2 = 0.f;
    if (tid < MAXI) {
      const float* dr = det + ((size_t)b * MAXI + tid) * 6;
      float y1 = dr[0], y2 = dr[2];
      bx1 = dr[1]; bx2 = dr[3];
      inb = (ys >= y1 && ys < y2);        // zero (padded) boxes cover nothing
    }
    unsigned long long bm = __ballot(inb);
    if (lane == 0) wmask[wv] = bm;
    __syncthreads();
    int n = __popcll(wmask[0]) + __popcll(wmask[1]);  // tid<100 in waves 0,1
    if (inb) {
      int pos = (wv ? __popcll(wmask[0]) : 0) +
                __popcll(bm & ((1ULL << lane) - 1ULL));
      lx1[pos] = bx1; lx2[pos] = bx2;
    }
    __syncthreads();
    float xs0 = ((float)tid + 0.5f) * (1.0f / 512.0f);
    float xs1 = ((float)(tid + 256) + 0.5f) * (1.0f / 512.0f);
    bool c0 = false, c1 = false;
    for (int t = 0; t < n; t++) {
      float a = lx1[t], bq = lx2[t];
      c0 = c0 || (xs0 >= a && xs0 < bq);
      c1 = c1 || (xs1 >= a && xs1 < bq);
    }
    float* rowp = mask + ((size_t)b * HH + h) * WW;
    rowp[tid] = c0 ? 1.0f : 0.0f;
    rowp[tid + 256] = c1 ? 1.0f : 0.0f;
  }
}

// ---------------------------------------------------------------------------
extern "C" void kernel_launch(void* const* d_in, const int* in_sizes, int n_in,
                              void* d_out, int out_size, void* d_ws, size_t ws_size,
                              hipStream_t stream) {
  const float* rois = (const float*)d_in[0];
  const float* probs = (const float*)d_in[1];
  const float* deltas = (const float*)d_in[2];
  const float* stdv = (const float*)d_in[3];
  float* out = (float*)d_out;
  float* det = out;                  // [8,100,6] = 4800 floats
  float* mask = out + BB * MAXI * 6; // [8,512,512]

  char* p = (char*)d_ws;
  unsigned long long* gkeys = (unsigned long long*)p; p += (size_t)BB * NPAD * 8;
  float* box     = (float*)p; p += (size_t)BB * NPAD * 16;
  float* score   = (float*)p; p += (size_t)BB * NPAD * 4;
  int*   cls     = (int*)p;   p += (size_t)BB * NPAD * 4;
  int*   valid   = (int*)p;   p += (size_t)BB * NPAD * 4;
  int*   partial = (int*)p;   p += (size_t)BB * 8 * NPAD * 4;
  int*   perm    = (int*)p;   p += (size_t)BB * NPAD * 4;

  void* args[] = {&rois, &probs, &deltas, &stdv, &score, &cls, &valid,
                  &box, &gkeys, &partial, &perm, &det, &mask};
  hipLaunchCooperativeKernel((const void*)k_fused, dim3(512), dim3(256),
                             args, 0, stream);
}

// Round 6
// 151.681 us; speedup vs baseline: 2.2916x; 2.2916x over previous
//
#include <hip/hip_runtime.h>
#include <math.h>

#define BB 8
#define NN 2000
#define CC 81
#define NPAD 2048
#define MAXI 100
#define HH 512
#define WW 512

// ---------------------------------------------------------------------------
// Kernel A: per-proposal class argmax, delta refine, validity, sort key.
// One wave (64 lanes) per proposal slot (padded to NPAD per batch). Coalesced
// prob reads, shuffle argmax. key = sortable(score if valid else -inf)<<32 |
// (0xFFFFFFFF - n): descending u64 order == stable argsort(score desc, idx asc).
// [R4-proven bit-exact]
// ---------------------------------------------------------------------------
__global__ void k_refine(const float* __restrict__ rois,
                         const float* __restrict__ probs,
                         const float* __restrict__ deltas,
                         const float* __restrict__ stdv,
                         float* __restrict__ score, int* __restrict__ cls,
                         int* __restrict__ valid, float* __restrict__ box,
                         unsigned long long* __restrict__ gkeys) {
#pragma clang fp contract(off)
  int g = blockIdx.x * 4 + (threadIdx.x >> 6);
  if (g >= BB * NPAD) return;
  int lane = threadIdx.x & 63;
  int b = g >> 11, n = g & (NPAD - 1);
  if (n >= NN) {                      // pad slot: sentinel key + invalid
    if (lane == 0) {
      unsigned u = __float_as_uint(-INFINITY);
      u = ~u;                         // sign set -> ~u
      gkeys[b * NPAD + n] =
          ((unsigned long long)u << 32) | (0xFFFFFFFFu - (unsigned)n);
      valid[b * NPAD + n] = 0;        // NMS may gather this slot; ws is poisoned
    }
    return;
  }
  const float* pp = probs + ((size_t)b * NN + n) * CC;
  float best = -INFINITY;
  int bc = CC;
  for (int c = lane; c < CC; c += 64) {
    float p = pp[c];
    if (p > best) { best = p; bc = c; }   // per-lane stride keeps first max
  }
  // cross-lane argmax, first-occurrence tie-break (smaller class wins)
  for (int off = 32; off; off >>= 1) {
    float ob = __shfl_xor(best, off, 64);
    int oc = __shfl_xor(bc, off, 64);
    if (ob > best || (ob == best && oc < bc)) { best = ob; bc = oc; }
  }
  if (lane == 0) {
    int idx = b * NPAD + n;
    const float* r = rois + ((size_t)b * NN + n) * 4;
    const float* dd = deltas + (((size_t)b * NN + n) * CC + bc) * 4;
    float d0 = dd[0] * stdv[0], d1 = dd[1] * stdv[1];
    float d2 = dd[2] * stdv[2], d3 = dd[3] * stdv[3];
    float y1 = r[0], x1 = r[1], y2 = r[2], x2 = r[3];
    float h = y2 - y1, w = x2 - x1;
    float cy = y1 + 0.5f * h + d0 * h;
    float cx = x1 + 0.5f * w + d1 * w;
    h = h * (float)exp((double)d2);   // double path ~= correctly-rounded f32 exp
    w = w * (float)exp((double)d3);
    float ny1 = cy - 0.5f * h, nx1 = cx - 0.5f * w;
    float ny2 = cy + 0.5f * h, nx2 = cx + 0.5f * w;
    ny1 = fminf(fmaxf(ny1, 0.f), 1.f);
    nx1 = fminf(fmaxf(nx1, 0.f), 1.f);
    ny2 = fminf(fmaxf(ny2, 0.f), 1.f);
    nx2 = fminf(fmaxf(nx2, 0.f), 1.f);
    box[idx * 4 + 0] = ny1;
    box[idx * 4 + 1] = nx1;
    box[idx * 4 + 2] = ny2;
    box[idx * 4 + 3] = nx2;
    score[idx] = best;
    cls[idx] = bc;
    int v = (bc > 0 && best >= 0.05f) ? 1 : 0;
    valid[idx] = v;
    float ks = v ? best : -INFINITY;
    unsigned u = __float_as_uint(ks);
    u = (u & 0x80000000u) ? ~u : (u | 0x80000000u);
    gkeys[idx] = ((unsigned long long)u << 32) | (0xFFFFFFFFu - (unsigned)n);
  }
}

// ---------------------------------------------------------------------------
// Kernel B (v5): fused sort + NMS, one block of 1024 threads per batch.
// Intra-block deps only -> no cross-block sync, one dispatch instead of
// three (R5 lesson: grid.sync ~60us on 8 non-coherent XCDs; dispatch gap
// only ~7us, so minimize dispatch COUNT, not just work).
//   Sort: bitonic on 2048 u64 keys in LDS, 66 passes, 1 exchange/thread/pass
//   (keys unique -> permutation identical to any stable argsort; R1-proven).
//   NMS: wave 0 runs the R4-proven greedy loop, gathering candidates through
//   idx = ~low32(sorted key); kept set register-resident; early-exit at 100.
// ---------------------------------------------------------------------------
__global__ void __launch_bounds__(1024)
k_sortnms(const unsigned long long* __restrict__ gkeys,
          const float* __restrict__ score, const int* __restrict__ cls,
          const int* __restrict__ valid, const float* __restrict__ box,
          float* __restrict__ det) {
#pragma clang fp contract(off)
  __shared__ unsigned long long skey[NPAD];
  int b = blockIdx.x, tid = threadIdx.x;
  skey[tid] = gkeys[b * NPAD + tid];
  skey[tid + 1024] = gkeys[b * NPAD + tid + 1024];
  for (unsigned k = 2; k <= NPAD; k <<= 1) {
    for (unsigned j = k >> 1; j > 0; j >>= 1) {
      __syncthreads();
      unsigned i = tid;                 // 1024 threads: exactly 2 elements each
      for (int rep = 0; rep < 2; rep++, i += 1024) {
        unsigned l = i ^ j;
        if (l > i) {
          unsigned long long a = skey[i], c = skey[l];
          bool desc = ((i & k) == 0);
          if (desc ? (a < c) : (a > c)) { skey[i] = c; skey[l] = a; }
        }
      }
    }
  }
  __syncthreads();
  if (tid >= 64) return;                // waves 1..15 done; LDS persists
  int lane = tid;
  int kept = 0;
  bool done = false;
  // register-resident kept boxes (offset coords) + area
  float k0y1 = 0.f, k0x1 = 0.f, k0y2 = 0.f, k0x2 = 0.f, k0a = 0.f;
  float k1y1 = 0.f, k1x1 = 0.f, k1y2 = 0.f, k1x2 = 0.f, k1a = 0.f;
  for (int base = 0; base < NN && !done; base += 64) {
    int pi = (int)(0xFFFFFFFFu - (unsigned)(skey[base + lane] & 0xFFFFFFFFu));
    int o = b * NPAD + pi;
    float4 bx = ((const float4*)box)[o];
    int lv = valid[o];
    int lc = cls[o];
    float lsc = score[o];
    int lim = (NN - base < 64) ? (NN - base) : 64;
    for (int j = 0; j < lim; j++) {
      int v = __shfl(lv, j, 64);
      if (!v) { done = true; break; }   // sorted: all invalid at the end
      float y1 = __shfl(bx.x, j, 64);
      float x1 = __shfl(bx.y, j, 64);
      float y2 = __shfl(bx.z, j, 64);
      float x2 = __shfl(bx.w, j, 64);
      int c = __shfl(lc, j, 64);
      float off = 2.0f * (float)c;
      float oy1 = y1 + off, ox1 = x1 + off, oy2 = y2 + off, ox2 = x2 + off;
      float area_i = (oy2 - oy1) * (ox2 - ox1);
      bool pred = false;
      if (lane < kept) {
        float yy1 = fmaxf(oy1, k0y1), xx1 = fmaxf(ox1, k0x1);
        float yy2 = fminf(oy2, k0y2), xx2 = fminf(ox2, k0x2);
        float inter = fmaxf(yy2 - yy1, 0.f) * fmaxf(xx2 - xx1, 0.f);
        float uni = (area_i + k0a) - inter;
        pred = (inter / fmaxf(uni, 1e-12f)) > 0.3f;
      }
      if (64 + lane < kept) {
        float yy1 = fmaxf(oy1, k1y1), xx1 = fmaxf(ox1, k1x1);
        float yy2 = fminf(oy2, k1y2), xx2 = fminf(ox2, k1x2);
        float inter = fmaxf(yy2 - yy1, 0.f) * fmaxf(xx2 - xx1, 0.f);
        float uni = (area_i + k1a) - inter;
        pred = pred || ((inter / fmaxf(uni, 1e-12f)) > 0.3f);
      }
      if (__ballot(pred) == 0ULL) {            // wave-uniform accept
        if (kept < 64) {
          if (lane == kept) { k0y1 = oy1; k0x1 = ox1; k0y2 = oy2; k0x2 = ox2; k0a = area_i; }
        } else {
          if (lane == kept - 64) { k1y1 = oy1; k1x1 = ox1; k1y2 = oy2; k1x2 = ox2; k1a = area_i; }
        }
        float sc = __shfl(lsc, j, 64);
        if (lane == 0) {
          float* dr = det + ((size_t)b * MAXI + kept) * 6;
          dr[0] = y1; dr[1] = x1; dr[2] = y2; dr[3] = x2;
          dr[4] = (float)c; dr[5] = sc;
        }
        kept++;
        if (kept == MAXI) { done = true; break; }
      }
    }
  }
  // zero-fill remaining det rows (d_out is poisoned 0xAA)
  int rem = (MAXI - kept) * 6;
  float* dr0 = det + ((size_t)b * MAXI + kept) * 6;
  for (int t = lane; t < rem; t += 64) dr0[t] = 0.f;
}

// ---------------------------------------------------------------------------
// Kernel C: attention mask. One block per (batch, row); 256 threads,
// 2 pixels per thread. Boxes covering this row's y compacted into LDS via
// ballot+popcount prefix, then per-pixel x tests (broadcast LDS reads).
// [R4-proven bit-exact]
// ---------------------------------------------------------------------------
__global__ void k_mask(const float* __restrict__ det, float* __restrict__ mask) {
  __shared__ float lx1[MAXI], lx2[MAXI];
  __shared__ unsigned long long wmask[4];
  int x = blockIdx.x;
  int h = x & (HH - 1);
  int b = x >> 9;
  int tid = threadIdx.x;
  int wv = tid >> 6, ln = tid & 63;
  float ys = ((float)h + 0.5f) * (1.0f / 512.0f);
  bool inb = false;
  float bx1 = 0.f, bx2 = 0.f;
  if (tid < MAXI) {
    const float* dr = det + ((size_t)b * MAXI + tid) * 6;
    float y1 = dr[0], y2 = dr[2];
    bx1 = dr[1]; bx2 = dr[3];
    inb = (ys >= y1 && ys < y2);   // zero (padded) boxes cover nothing
  }
  unsigned long long bm = __ballot(inb);
  if (ln == 0) wmask[wv] = bm;
  __syncthreads();
  int n = __popcll(wmask[0]) + __popcll(wmask[1]);  // tid<100 only in waves 0,1
  if (inb) {
    int pos = (wv ? __popcll(wmask[0]) : 0) +
              __popcll(bm & ((1ULL << ln) - 1ULL));
    lx1[pos] = bx1; lx2[pos] = bx2;
  }
  __syncthreads();
  float xs0 = ((float)tid + 0.5f) * (1.0f / 512.0f);
  float xs1 = ((float)(tid + 256) + 0.5f) * (1.0f / 512.0f);
  bool c0 = false, c1 = false;
  for (int t = 0; t < n; t++) {
    float a = lx1[t], bq = lx2[t];
    c0 = c0 || (xs0 >= a && xs0 < bq);
    c1 = c1 || (xs1 >= a && xs1 < bq);
  }
  float* row = mask + ((size_t)b * HH + h) * WW;
  row[tid] = c0 ? 1.0f : 0.0f;
  row[tid + 256] = c1 ? 1.0f : 0.0f;
}

// ---------------------------------------------------------------------------
extern "C" void kernel_launch(void* const* d_in, const int* in_sizes, int n_in,
                              void* d_out, int out_size, void* d_ws, size_t ws_size,
                              hipStream_t stream) {
  const float* rois = (const float*)d_in[0];
  const float* probs = (const float*)d_in[1];
  const float* deltas = (const float*)d_in[2];
  const float* stdv = (const float*)d_in[3];
  float* out = (float*)d_out;
  float* det = out;                  // [8,100,6] = 4800 floats
  float* mask = out + BB * MAXI * 6; // [8,512,512]

  char* p = (char*)d_ws;
  unsigned long long* gkeys = (unsigned long long*)p; p += (size_t)BB * NPAD * 8;
  float* box     = (float*)p; p += (size_t)BB * NPAD * 16;
  float* score   = (float*)p; p += (size_t)BB * NPAD * 4;
  int*   cls     = (int*)p;   p += (size_t)BB * NPAD * 4;
  int*   valid   = (int*)p;   p += (size_t)BB * NPAD * 4;

  k_refine<<<(BB * NPAD) / 4, 256, 0, stream>>>(rois, probs, deltas, stdv,
                                                score, cls, valid, box, gkeys);
  k_sortnms<<<BB, 1024, 0, stream>>>(gkeys, score, cls, valid, box, det);
  k_mask<<<BB * HH, 256, 0, stream>>>(det, mask);
}

// Round 7
// 136.290 us; speedup vs baseline: 2.5503x; 1.1129x over previous
//
#include <hip/hip_runtime.h>
#include <math.h>

#define BB 8
#define NN 2000
#define CC 81
#define NPAD 2048
#define MAXI 100
#define HH 512
#define WW 512

// ---------------------------------------------------------------------------
// Kernel A: per-proposal class argmax, delta refine, validity, sort key.
// One wave (64 lanes) per proposal slot (padded to NPAD per batch). Coalesced
// prob reads, shuffle argmax. key = sortable(score if valid else -inf)<<32 |
// (0xFFFFFFFF - n): descending u64 order == stable argsort(score desc, idx asc).
// [R4-proven bit-exact]
// ---------------------------------------------------------------------------
__global__ void k_refine(const float* __restrict__ rois,
                         const float* __restrict__ probs,
                         const float* __restrict__ deltas,
                         const float* __restrict__ stdv,
                         float* __restrict__ score, int* __restrict__ cls,
                         int* __restrict__ valid, float* __restrict__ box,
                         unsigned long long* __restrict__ gkeys) {
#pragma clang fp contract(off)
  int g = blockIdx.x * 4 + (threadIdx.x >> 6);
  if (g >= BB * NPAD) return;
  int lane = threadIdx.x & 63;
  int b = g >> 11, n = g & (NPAD - 1);
  if (n >= NN) {                      // pad slot: sentinel key + invalid
    if (lane == 0) {
      unsigned u = __float_as_uint(-INFINITY);
      u = ~u;                         // sign set -> ~u
      gkeys[b * NPAD + n] =
          ((unsigned long long)u << 32) | (0xFFFFFFFFu - (unsigned)n);
      valid[b * NPAD + n] = 0;        // NMS may gather this slot; ws is poisoned
    }
    return;
  }
  const float* pp = probs + ((size_t)b * NN + n) * CC;
  float best = -INFINITY;
  int bc = CC;
  for (int c = lane; c < CC; c += 64) {
    float p = pp[c];
    if (p > best) { best = p; bc = c; }   // per-lane stride keeps first max
  }
  // cross-lane argmax, first-occurrence tie-break (smaller class wins)
  for (int off = 32; off; off >>= 1) {
    float ob = __shfl_xor(best, off, 64);
    int oc = __shfl_xor(bc, off, 64);
    if (ob > best || (ob == best && oc < bc)) { best = ob; bc = oc; }
  }
  if (lane == 0) {
    int idx = b * NPAD + n;
    const float* r = rois + ((size_t)b * NN + n) * 4;
    const float* dd = deltas + (((size_t)b * NN + n) * CC + bc) * 4;
    float d0 = dd[0] * stdv[0], d1 = dd[1] * stdv[1];
    float d2 = dd[2] * stdv[2], d3 = dd[3] * stdv[3];
    float y1 = r[0], x1 = r[1], y2 = r[2], x2 = r[3];
    float h = y2 - y1, w = x2 - x1;
    float cy = y1 + 0.5f * h + d0 * h;
    float cx = x1 + 0.5f * w + d1 * w;
    h = h * (float)exp((double)d2);   // double path ~= correctly-rounded f32 exp
    w = w * (float)exp((double)d3);
    float ny1 = cy - 0.5f * h, nx1 = cx - 0.5f * w;
    float ny2 = cy + 0.5f * h, nx2 = cx + 0.5f * w;
    ny1 = fminf(fmaxf(ny1, 0.f), 1.f);
    nx1 = fminf(fmaxf(nx1, 0.f), 1.f);
    ny2 = fminf(fmaxf(ny2, 0.f), 1.f);
    nx2 = fminf(fmaxf(nx2, 0.f), 1.f);
    box[idx * 4 + 0] = ny1;
    box[idx * 4 + 1] = nx1;
    box[idx * 4 + 2] = ny2;
    box[idx * 4 + 3] = nx2;
    score[idx] = best;
    cls[idx] = bc;
    int v = (bc > 0 && best >= 0.05f) ? 1 : 0;
    valid[idx] = v;
    float ks = v ? best : -INFINITY;
    unsigned u = __float_as_uint(ks);
    u = (u & 0x80000000u) ? ~u : (u | 0x80000000u);
    gkeys[idx] = ((unsigned long long)u << 32) | (0xFFFFFFFFu - (unsigned)n);
  }
}

// ---------------------------------------------------------------------------
// Kernel B: partial rank counts, CHIP-WIDE (512 blocks) — R6 lesson: N^2 rank
// is only cheap spread across CUs; in-block sorts are barrier/VALU-bound.
// Grid = (batch, i-part, j-part). Each thread owns key i (register) and scans
// a 256-key j-chunk staged in LDS (broadcast, conflict-free). [R4-proven]
// ---------------------------------------------------------------------------
__global__ void k_rankp(const unsigned long long* __restrict__ gkeys,
                        int* __restrict__ partial) {
  __shared__ unsigned long long sk[256];
  int blk = blockIdx.x;                 // b*64 + ip*8 + jp
  int jp = blk & 7, ip = (blk >> 3) & 7, b = blk >> 6;
  int tid = threadIdx.x;
  sk[tid] = gkeys[b * NPAD + jp * 256 + tid];
  unsigned long long myk = gkeys[b * NPAD + ip * 256 + tid];
  __syncthreads();
  int cnt = 0;
#pragma unroll 8
  for (int j = 0; j < 256; j++) cnt += (sk[j] > myk) ? 1 : 0;
  partial[(b * 8 + jp) * NPAD + ip * 256 + tid] = cnt;
}

// ---------------------------------------------------------------------------
// Kernel C (v6): fused perm + NMS, one block of 256 threads per batch.
// Sums the 8 partials per element -> rank (a perfect permutation since keys
// are unique), scatters perm[rank]=i directly into LDS (k_perm's global
// round-trip + one dispatch gap removed vs R4). Then wave 0 runs the
// R4-proven greedy NMS: candidates gathered 64 at a time through sperm,
// broadcast via shuffles; kept set register-resident (slot0: idx==lane,
// slot1: idx==64+lane); early-exit at kept==100 (== top_k of kept since
// order is score-sorted). Per-class count<100 is vacuous before total kept
// reaches 100; cross-class IoU is 0 by the class-offset trick.
// ---------------------------------------------------------------------------
__global__ void __launch_bounds__(256)
k_permnms(const int* __restrict__ partial, const float* __restrict__ score,
          const int* __restrict__ cls, const int* __restrict__ valid,
          const float* __restrict__ box, float* __restrict__ det) {
#pragma clang fp contract(off)
  __shared__ int sperm[NPAD];
  int b = blockIdx.x, tid = threadIdx.x;
  for (int e = tid; e < NPAD; e += 256) {
    int rank = 0;
#pragma unroll
    for (int jp = 0; jp < 8; jp++) rank += partial[(b * 8 + jp) * NPAD + e];
    sperm[rank] = e;
  }
  __syncthreads();
  if (tid >= 64) return;                // waves 1..3 done; LDS persists
  int lane = tid;
  int kept = 0;
  bool done = false;
  // register-resident kept boxes (offset coords) + area
  float k0y1 = 0.f, k0x1 = 0.f, k0y2 = 0.f, k0x2 = 0.f, k0a = 0.f;
  float k1y1 = 0.f, k1x1 = 0.f, k1y2 = 0.f, k1x2 = 0.f, k1a = 0.f;
  for (int base = 0; base < NN && !done; base += 64) {
    int pi = sperm[base + lane];
    int o = b * NPAD + pi;
    float4 bx = ((const float4*)box)[o];
    int lv = valid[o];
    int lc = cls[o];
    float lsc = score[o];
    int lim = (NN - base < 64) ? (NN - base) : 64;
    for (int j = 0; j < lim; j++) {
      int v = __shfl(lv, j, 64);
      if (!v) { done = true; break; }   // sorted: all invalid at the end
      float y1 = __shfl(bx.x, j, 64);
      float x1 = __shfl(bx.y, j, 64);
      float y2 = __shfl(bx.z, j, 64);
      float x2 = __shfl(bx.w, j, 64);
      int c = __shfl(lc, j, 64);
      float off = 2.0f * (float)c;
      float oy1 = y1 + off, ox1 = x1 + off, oy2 = y2 + off, ox2 = x2 + off;
      float area_i = (oy2 - oy1) * (ox2 - ox1);
      bool pred = false;
      if (lane < kept) {
        float yy1 = fmaxf(oy1, k0y1), xx1 = fmaxf(ox1, k0x1);
        float yy2 = fminf(oy2, k0y2), xx2 = fminf(ox2, k0x2);
        float inter = fmaxf(yy2 - yy1, 0.f) * fmaxf(xx2 - xx1, 0.f);
        float uni = (area_i + k0a) - inter;
        pred = (inter / fmaxf(uni, 1e-12f)) > 0.3f;
      }
      if (64 + lane < kept) {
        float yy1 = fmaxf(oy1, k1y1), xx1 = fmaxf(ox1, k1x1);
        float yy2 = fminf(oy2, k1y2), xx2 = fminf(ox2, k1x2);
        float inter = fmaxf(yy2 - yy1, 0.f) * fmaxf(xx2 - xx1, 0.f);
        float uni = (area_i + k1a) - inter;
        pred = pred || ((inter / fmaxf(uni, 1e-12f)) > 0.3f);
      }
      if (__ballot(pred) == 0ULL) {            // wave-uniform accept
        if (kept < 64) {
          if (lane == kept) { k0y1 = oy1; k0x1 = ox1; k0y2 = oy2; k0x2 = ox2; k0a = area_i; }
        } else {
          if (lane == kept - 64) { k1y1 = oy1; k1x1 = ox1; k1y2 = oy2; k1x2 = ox2; k1a = area_i; }
        }
        float sc = __shfl(lsc, j, 64);
        if (lane == 0) {
          float* dr = det + ((size_t)b * MAXI + kept) * 6;
          dr[0] = y1; dr[1] = x1; dr[2] = y2; dr[3] = x2;
          dr[4] = (float)c; dr[5] = sc;
        }
        kept++;
        if (kept == MAXI) { done = true; break; }
      }
    }
  }
  // zero-fill remaining det rows (d_out is poisoned 0xAA)
  int rem = (MAXI - kept) * 6;
  float* dr0 = det + ((size_t)b * MAXI + kept) * 6;
  for (int t = lane; t < rem; t += 64) dr0[t] = 0.f;
}

// ---------------------------------------------------------------------------
// Kernel D: attention mask. One block per (batch, row); 256 threads,
// 2 pixels per thread. Boxes covering this row's y compacted into LDS via
// ballot+popcount prefix, then per-pixel x tests (broadcast LDS reads).
// [R4-proven bit-exact]
// ---------------------------------------------------------------------------
__global__ void k_mask(const float* __restrict__ det, float* __restrict__ mask) {
  __shared__ float lx1[MAXI], lx2[MAXI];
  __shared__ unsigned long long wmask[4];
  int x = blockIdx.x;
  int h = x & (HH - 1);
  int b = x >> 9;
  int tid = threadIdx.x;
  int wv = tid >> 6, ln = tid & 63;
  float ys = ((float)h + 0.5f) * (1.0f / 512.0f);
  bool inb = false;
  float bx1 = 0.f, bx2 = 0.f;
  if (tid < MAXI) {
    const float* dr = det + ((size_t)b * MAXI + tid) * 6;
    float y1 = dr[0], y2 = dr[2];
    bx1 = dr[1]; bx2 = dr[3];
    inb = (ys >= y1 && ys < y2);   // zero (padded) boxes cover nothing
  }
  unsigned long long bm = __ballot(inb);
  if (ln == 0) wmask[wv] = bm;
  __syncthreads();
  int n = __popcll(wmask[0]) + __popcll(wmask[1]);  // tid<100 only in waves 0,1
  if (inb) {
    int pos = (wv ? __popcll(wmask[0]) : 0) +
              __popcll(bm & ((1ULL << ln) - 1ULL));
    lx1[pos] = bx1; lx2[pos] = bx2;
  }
  __syncthreads();
  float xs0 = ((float)tid + 0.5f) * (1.0f / 512.0f);
  float xs1 = ((float)(tid + 256) + 0.5f) * (1.0f / 512.0f);
  bool c0 = false, c1 = false;
  for (int t = 0; t < n; t++) {
    float a = lx1[t], bq = lx2[t];
    c0 = c0 || (xs0 >= a && xs0 < bq);
    c1 = c1 || (xs1 >= a && xs1 < bq);
  }
  float* row = mask + ((size_t)b * HH + h) * WW;
  row[tid] = c0 ? 1.0f : 0.0f;
  row[tid + 256] = c1 ? 1.0f : 0.0f;
}

// ---------------------------------------------------------------------------
extern "C" void kernel_launch(void* const* d_in, const int* in_sizes, int n_in,
                              void* d_out, int out_size, void* d_ws, size_t ws_size,
                              hipStream_t stream) {
  const float* rois = (const float*)d_in[0];
  const float* probs = (const float*)d_in[1];
  const float* deltas = (const float*)d_in[2];
  const float* stdv = (const float*)d_in[3];
  float* out = (float*)d_out;
  float* det = out;                  // [8,100,6] = 4800 floats
  float* mask = out + BB * MAXI * 6; // [8,512,512]

  char* p = (char*)d_ws;
  unsigned long long* gkeys = (unsigned long long*)p; p += (size_t)BB * NPAD * 8;
  float* box     = (float*)p; p += (size_t)BB * NPAD * 16;
  float* score   = (float*)p; p += (size_t)BB * NPAD * 4;
  int*   cls     = (int*)p;   p += (size_t)BB * NPAD * 4;
  int*   valid   = (int*)p;   p += (size_t)BB * NPAD * 4;
  int*   partial = (int*)p;   p += (size_t)BB * 8 * NPAD * 4;

  k_refine<<<(BB * NPAD) / 4, 256, 0, stream>>>(rois, probs, deltas, stdv,
                                                score, cls, valid, box, gkeys);
  k_rankp<<<BB * 64, 256, 0, stream>>>(gkeys, partial);
  k_permnms<<<BB, 256, 0, stream>>>(partial, score, cls, valid, box, det);
  k_mask<<<BB * HH, 256, 0, stream>>>(det, mask);
}